// Round 9
// baseline (410.519 us; speedup 1.0000x reference)
//
#include <hip/hip_runtime.h>

#define NUM_USERS 100000
#define NUM_ITEMS 50000
#define NNZ       2400000
#define EMB       64
#define NTOT      (NUM_USERS + NUM_ITEMS)
#define NQ        16384
#define NBKT      ((NTOT + 63) / 64)          // 2344 buckets of 64 rows
#define NAB       ((NNZ + 4095) / 4096)       // append blocks = 586
#define SPILLCAP  32768

// ---------- nt helpers ----------
__device__ __forceinline__ int nt_load_i(const int* p) {
    return __builtin_nontemporal_load(p);
}
__device__ __forceinline__ float nt_load_f(const float* p) {
    return __builtin_nontemporal_load(p);
}
__device__ __forceinline__ int2 nt_load_i2(const int2* p) {
    unsigned long long u = __builtin_nontemporal_load((const unsigned long long*)p);
    int2 r; r.x = (int)(u & 0xFFFFFFFFull); r.y = (int)(u >> 32);
    return r;
}

// ---------- shared small kernels ----------

__global__ void init_cur_kernel(const float* __restrict__ eu,
                                const float* __restrict__ ei,
                                float* __restrict__ cur) {
    int idx = blockIdx.x * blockDim.x + threadIdx.x;           // float4 index
    const int total4 = NTOT * EMB / 4;
    const int user4  = NUM_USERS * EMB / 4;
    if (idx < total4) {
        float4 v;
        if (idx < user4) v = ((const float4*)eu)[idx];
        else             v = ((const float4*)ei)[idx - user4];
        ((float4*)cur)[idx] = v;
    }
}

template <bool STORE>
__global__ void gather_acc_kernel(const int* __restrict__ users,
                                  const int* __restrict__ items,
                                  const float* __restrict__ src,
                                  float* __restrict__ uacc,
                                  float* __restrict__ iacc) {
    int idx = blockIdx.x * blockDim.x + threadIdx.x;
    if (idx >= NQ * 16) return;
    int j = idx >> 4;
    int t = idx & 15;
    int u  = users[j];
    int it = items[j] + NUM_USERS;
    float4 uv = ((const float4*)src)[(size_t)u  * 16 + t];
    float4 iv = ((const float4*)src)[(size_t)it * 16 + t];
    float4* up = (float4*)uacc + idx;
    float4* ip = (float4*)iacc + idx;
    if (STORE) { *up = uv; *ip = iv; }
    else {
        float4 a = *up, b = *ip;
        a.x += uv.x; a.y += uv.y; a.z += uv.z; a.w += uv.w;
        b.x += iv.x; b.y += iv.y; b.z += iv.z; b.w += iv.w;
        *up = a; *ip = b;
    }
}

__global__ void dot_kernel(const float* __restrict__ uacc,
                           const float* __restrict__ iacc,
                           float* __restrict__ out) {
    int idx = blockIdx.x * blockDim.x + threadIdx.x;
    int j = idx >> 6;
    if (j >= NQ) return;
    int d = idx & 63;
    float p = uacc[(size_t)j * EMB + d] * iacc[(size_t)j * EMB + d];
    #pragma unroll
    for (int o = 32; o > 0; o >>= 1) p += __shfl_down(p, o);
    if (d == 0) out[j] = p * (1.0f / 16.0f);
}

// ---------- build: LDS-aggregated fixed-capacity bucket append ----------

__global__ __launch_bounds__(1024) void append_agg_kernel(
        const int* __restrict__ row,
        const int* __restrict__ col,
        const float* __restrict__ val,
        int* __restrict__ ctr,
        int2* __restrict__ staging,
        int4* __restrict__ spill,
        int* __restrict__ spillcnt,
        int bcap) {
    __shared__ int cnt[NBKT];
    __shared__ int base[NBKT];
    int tid = threadIdx.x;
    for (int k = tid; k < NBKT; k += 1024) cnt[k] = 0;
    __syncthreads();

    int  myb[4], myr[4];
    int2 rec[4];
    int  rr[4], cc[4];
    int e0 = blockIdx.x * 4096 + tid;
    #pragma unroll
    for (int j = 0; j < 4; ++j) {
        int e = e0 + 1024 * j;
        if (e < NNZ) {
            int r = nt_load_i(&row[e]);
            int c = nt_load_i(&col[e]);
            float v = nt_load_f(&val[e]);
            int b = ((unsigned)r) >> 6;
            myb[j] = b;
            rr[j] = r; cc[j] = c;
            rec[j] = make_int2(((r & 63) << 18) | c, __float_as_int(v));
            myr[j] = atomicAdd(&cnt[b], 1);          // local rank
        } else {
            myb[j] = -1;
        }
    }
    __syncthreads();
    for (int k = tid; k < NBKT; k += 1024) {
        int c = cnt[k];
        base[k] = c ? atomicAdd(&ctr[k], c) : 0;     // one grant per nonzero bucket
    }
    __syncthreads();
    #pragma unroll
    for (int j = 0; j < 4; ++j) {
        if (myb[j] < 0) continue;
        int p = base[myb[j]] + myr[j];
        if (p < bcap) {
            staging[(size_t)myb[j] * bcap + p] = rec[j];
        } else {
            int sp = atomicAdd(spillcnt, 1);
            if (sp < SPILLCAP) spill[sp] = make_int4(rr[j], cc[j], rec[j].y, 0);
        }
    }
}

// ---------- within-bucket sort -> CSR (in place, fixed segments) ----------

__global__ __launch_bounds__(256) void csr_fixed_kernel(
        const int* __restrict__ ctr,
        int2* __restrict__ staging,
        int* __restrict__ rs65,
        int bcap) {
    __shared__ int2 recs[1216];
    __shared__ int cnt[64];
    __shared__ int pos[64];
    int tid = threadIdx.x;
    int b = blockIdx.x;
    int base0 = b * bcap;
    int n = min(ctr[b], bcap);

    if (tid < 64) cnt[tid] = 0;
    __syncthreads();
    for (int k = tid; k < n; k += 256) {
        int2 rec = nt_load_i2(&staging[base0 + k]);
        recs[k] = rec;
        atomicAdd(&cnt[((unsigned)rec.x) >> 18], 1);
    }
    __syncthreads();
    if (tid == 0) {
        int run = 0;
        #pragma unroll
        for (int i = 0; i < 64; ++i) { pos[i] = run; run += cnt[i]; }
    }
    __syncthreads();
    if (tid < 64) rs65[b * 65 + tid] = base0 + pos[tid];
    if (tid == 65) rs65[b * 65 + 64] = base0 + n;
    __syncthreads();
    for (int k = tid; k < n; k += 256) {
        int2 rec = recs[k];
        int rl = ((unsigned)rec.x) >> 18;
        int p = atomicAdd(&pos[rl], 1);
        staging[base0 + p] = make_int2(rec.x & 0x3FFFF, rec.y);
    }
}

// ---------- SpMM: one 16-lane group per row (4 rows per wave) ----------
// No cross-lane reduce; 4-edge inner unroll keeps 4 gather instructions
// (32x128B lines) in flight per wave.

__global__ __launch_bounds__(256) void spmm_csr_kernel(
        const int* __restrict__ rs65,
        const int2* __restrict__ pairs,
        const float* __restrict__ cur,
        float* __restrict__ next) {
    int gid = blockIdx.x * blockDim.x + threadIdx.x;
    int grp = gid >> 4;                 // 16-lane group = row
    if (grp >= NTOT) return;
    int t = threadIdx.x & 15;           // dim quarter
    int r = grp;
    int b = r >> 6, i = r & 63;
    int s = rs65[b * 65 + i];
    int e = rs65[b * 65 + i + 1];
    float4 acc = make_float4(0.f, 0.f, 0.f, 0.f);
    for (int i0 = s; i0 < e; i0 += 4) {
        int   c[4];
        float v[4];
        #pragma unroll
        for (int k = 0; k < 4; ++k) {
            int idx = i0 + k;
            bool ok = idx < e;
            int2 cv = nt_load_i2(&pairs[ok ? idx : s]);
            c[k] = cv.x;
            v[k] = ok ? __int_as_float(cv.y) : 0.f;
        }
        #pragma unroll
        for (int k = 0; k < 4; ++k) {
            float4 g = *(const float4*)&cur[(size_t)c[k] * EMB + t * 4];
            acc.x += v[k] * g.x; acc.y += v[k] * g.y;
            acc.z += v[k] * g.z; acc.w += v[k] * g.w;
        }
    }
    ((float4*)&next[(size_t)r * EMB])[t] = acc;
}

// spill edges (normally zero): atomic add on top of spmm output
__global__ void spill_apply_kernel(const int4* __restrict__ spill,
                                   const int* __restrict__ spillcnt,
                                   const float* __restrict__ cur,
                                   float* __restrict__ next) {
    int n = min(*spillcnt, SPILLCAP);
    for (int idx = blockIdx.x * blockDim.x + threadIdx.x;
         idx < n * EMB; idx += gridDim.x * blockDim.x) {
        int e = idx >> 6, d = idx & 63;
        int4 rec = spill[e];
        atomicAdd(&next[(size_t)rec.x * EMB + d],
                  __int_as_float(rec.z) * cur[(size_t)rec.y * EMB + d]);
    }
}

// ---------- fallback atomic SpMM (ws too small) ----------

__global__ void spmm_atomic_kernel(const int* __restrict__ row,
                                   const int* __restrict__ col,
                                   const float* __restrict__ val,
                                   const float* __restrict__ cur,
                                   float* __restrict__ next) {
    long long idx = (long long)blockIdx.x * blockDim.x + threadIdx.x;
    if (idx >= (long long)NNZ * EMB) return;
    int e = (int)(idx >> 6);
    int d = (int)(idx & 63);
    atomicAdd(&next[row[e] * EMB + d], val[e] * cur[col[e] * EMB + d]);
}

extern "C" void kernel_launch(void* const* d_in, const int* in_sizes, int n_in,
                              void* d_out, int out_size, void* d_ws, size_t ws_size,
                              hipStream_t stream) {
    const int*   row   = (const int*)d_in[0];
    const int*   col   = (const int*)d_in[1];
    const float* val   = (const float*)d_in[2];
    const float* eu    = (const float*)d_in[3];
    const float* ei    = (const float*)d_in[4];
    const int*   users = (const int*)d_in[5];
    const int*   items = (const int*)d_in[6];
    float*       out   = (float*)d_out;

    // fixed part of workspace
    float* bufA = (float*)d_ws;                          // NTOT*EMB
    float* bufB = bufA + (size_t)NTOT * EMB;             // NTOT*EMB
    float* uacc = bufB + (size_t)NTOT * EMB;             // NQ*EMB
    float* iacc = uacc + (size_t)NQ * EMB;               // NQ*EMB
    int*   ctr  = (int*)(iacc + (size_t)NQ * EMB);       // NBKT
    int*   rs65 = ctr + NBKT;                            // NBKT*65
    int*   spillcnt = rs65 + NBKT * 65;                  // 1 (+pad to 4)
    int4*  spill = (int4*)(spillcnt + 4);                // SPILLCAP
    int2*  staging = (int2*)(spill + SPILLCAP);          // NBKT*bcap

    size_t fixed_bytes = (size_t)((char*)staging - (char*)d_ws);
    size_t need1216 = fixed_bytes + (size_t)NBKT * 1216 * sizeof(int2);
    size_t need1024 = fixed_bytes + (size_t)NBKT * 1024 * sizeof(int2);
    int bcap = (ws_size >= need1216) ? 1216 : ((ws_size >= need1024) ? 1024 : 0);

    init_cur_kernel<<<(NTOT * EMB / 4 + 255) / 256, 256, 0, stream>>>(eu, ei, bufA);
    gather_acc_kernel<true><<<(NQ * 16 + 255) / 256, 256, 0, stream>>>(users, items, bufA, uacc, iacc);

    float* cur = bufA;
    float* nxt = bufB;

    if (bcap > 0) {
        hipMemsetAsync(ctr, 0, NBKT * sizeof(int), stream);
        hipMemsetAsync(spillcnt, 0, 4 * sizeof(int), stream);
        append_agg_kernel<<<NAB, 1024, 0, stream>>>(row, col, val, ctr, staging,
                                                    spill, spillcnt, bcap);
        csr_fixed_kernel<<<NBKT, 256, 0, stream>>>(ctr, staging, rs65, bcap);

        for (int l = 0; l < 3; ++l) {
            spmm_csr_kernel<<<(NTOT * 16 + 255) / 256, 256, 0, stream>>>(rs65, staging, cur, nxt);
            spill_apply_kernel<<<512, 256, 0, stream>>>(spill, spillcnt, cur, nxt);
            gather_acc_kernel<false><<<(NQ * 16 + 255) / 256, 256, 0, stream>>>(users, items, nxt, uacc, iacc);
            float* t = cur; cur = nxt; nxt = t;
        }
    } else {
        // fallback: atomic SpMM
        const long long spmm_threads = (long long)NNZ * EMB;
        for (int l = 0; l < 3; ++l) {
            hipMemsetAsync(nxt, 0, (size_t)NTOT * EMB * sizeof(float), stream);
            spmm_atomic_kernel<<<(int)((spmm_threads + 255) / 256), 256, 0, stream>>>(row, col, val, cur, nxt);
            gather_acc_kernel<false><<<(NQ * 16 + 255) / 256, 256, 0, stream>>>(users, items, nxt, uacc, iacc);
            float* t = cur; cur = nxt; nxt = t;
        }
    }

    dot_kernel<<<(NQ * EMB + 255) / 256, 256, 0, stream>>>(uacc, iacc, out);
}

// Round 11
// 366.516 us; speedup vs baseline: 1.1201x; 1.1201x over previous
//
#include <hip/hip_runtime.h>

#define NUM_USERS 100000
#define NUM_ITEMS 50000
#define NNZ       2400000
#define EMB       64
#define NTOT      (NUM_USERS + NUM_ITEMS)
#define NQ        16384
#define NBKT      ((NTOT + 63) / 64)          // 2344 buckets of 64 rows
#define NAB       ((NNZ + 4095) / 4096)       // append blocks = 586
#define SPILLCAP  32768

// ---------- nt helper (scalar element type only) ----------
__device__ __forceinline__ int2 nt_load_i2(const int2* p) {
    unsigned long long u = __builtin_nontemporal_load((const unsigned long long*)p);
    int2 r; r.x = (int)(u & 0xFFFFFFFFull); r.y = (int)(u >> 32);
    return r;
}

// ---------- shared small kernels ----------

__global__ void init_cur_kernel(const float* __restrict__ eu,
                                const float* __restrict__ ei,
                                float* __restrict__ cur) {
    int idx = blockIdx.x * blockDim.x + threadIdx.x;           // float4 index
    const int total4 = NTOT * EMB / 4;
    const int user4  = NUM_USERS * EMB / 4;
    if (idx < total4) {
        float4 v;
        if (idx < user4) v = ((const float4*)eu)[idx];
        else             v = ((const float4*)ei)[idx - user4];
        ((float4*)cur)[idx] = v;
    }
}

template <bool STORE>
__global__ void gather_acc_kernel(const int* __restrict__ users,
                                  const int* __restrict__ items,
                                  const float* __restrict__ src,
                                  float* __restrict__ uacc,
                                  float* __restrict__ iacc) {
    int idx = blockIdx.x * blockDim.x + threadIdx.x;
    if (idx >= NQ * 16) return;
    int j = idx >> 4;
    int t = idx & 15;
    int u  = users[j];
    int it = items[j] + NUM_USERS;
    float4 uv = ((const float4*)src)[(size_t)u  * 16 + t];
    float4 iv = ((const float4*)src)[(size_t)it * 16 + t];
    float4* up = (float4*)uacc + idx;
    float4* ip = (float4*)iacc + idx;
    if (STORE) { *up = uv; *ip = iv; }
    else {
        float4 a = *up, b = *ip;
        a.x += uv.x; a.y += uv.y; a.z += uv.z; a.w += uv.w;
        b.x += iv.x; b.y += iv.y; b.z += iv.z; b.w += iv.w;
        *up = a; *ip = b;
    }
}

__global__ void dot_kernel(const float* __restrict__ uacc,
                           const float* __restrict__ iacc,
                           float* __restrict__ out) {
    int idx = blockIdx.x * blockDim.x + threadIdx.x;
    int j = idx >> 6;
    if (j >= NQ) return;
    int d = idx & 63;
    float p = uacc[(size_t)j * EMB + d] * iacc[(size_t)j * EMB + d];
    #pragma unroll
    for (int o = 32; o > 0; o >>= 1) p += __shfl_down(p, o);
    if (d == 0) out[j] = p * (1.0f / 16.0f);
}

// ---------- build: LDS-aggregated fixed-capacity bucket append ----------
// Each thread ingests 4 CONSECUTIVE edges via int4/float4 loads (3 coalesced
// 16B loads). Rank via LDS atomics; one global atomic grant per
// (block, nonzero bucket); stores land bucket-local (frontier merges in L2).

__global__ __launch_bounds__(1024) void append_agg_kernel(
        const int* __restrict__ row,
        const int* __restrict__ col,
        const float* __restrict__ val,
        int* __restrict__ ctr,
        int2* __restrict__ staging,
        int4* __restrict__ spill,
        int* __restrict__ spillcnt,
        int bcap) {
    __shared__ int cnt[NBKT];
    __shared__ int base[NBKT];
    int tid = threadIdx.x;
    for (int k = tid; k < NBKT; k += 1024) cnt[k] = 0;
    __syncthreads();

    int  myb[4], myr[4];
    int2 rec[4];
    int  rr[4], cc[4];
    int e0 = (blockIdx.x * 1024 + tid) * 4;
    bool any = (e0 < NNZ);                       // NNZ % 4 == 0 -> all-or-none
    if (any) {
        int4   r4 = *(const int4*)&row[e0];
        int4   c4 = *(const int4*)&col[e0];
        float4 v4 = *(const float4*)&val[e0];
        int   rs_[4] = {r4.x, r4.y, r4.z, r4.w};
        int   cs_[4] = {c4.x, c4.y, c4.z, c4.w};
        float vs_[4] = {v4.x, v4.y, v4.z, v4.w};
        #pragma unroll
        for (int j = 0; j < 4; ++j) {
            int r = rs_[j];
            int b = ((unsigned)r) >> 6;
            myb[j] = b;
            rr[j] = r; cc[j] = cs_[j];
            rec[j] = make_int2(((r & 63) << 18) | cs_[j], __float_as_int(vs_[j]));
            myr[j] = atomicAdd(&cnt[b], 1);      // local rank
        }
    } else {
        #pragma unroll
        for (int j = 0; j < 4; ++j) myb[j] = -1;
    }
    __syncthreads();
    for (int k = tid; k < NBKT; k += 1024) {
        int c = cnt[k];
        base[k] = c ? atomicAdd(&ctr[k], c) : 0; // one grant per nonzero bucket
    }
    __syncthreads();
    if (any) {
        #pragma unroll
        for (int j = 0; j < 4; ++j) {
            int p = base[myb[j]] + myr[j];
            if (p < bcap) {
                staging[(size_t)myb[j] * bcap + p] = rec[j];
            } else {
                int sp = atomicAdd(spillcnt, 1);
                if (sp < SPILLCAP) spill[sp] = make_int4(rr[j], cc[j], rec[j].y, 0);
            }
        }
    }
}

// ---------- within-bucket sort -> CSR (in place, fixed segments) ----------

__global__ __launch_bounds__(512) void csr_fixed_kernel(
        const int* __restrict__ ctr,
        int2* __restrict__ staging,
        int* __restrict__ rs65,
        int bcap) {
    __shared__ int2 recs[1216];
    __shared__ int cnt[64];
    __shared__ int pos[64];
    int tid = threadIdx.x;
    int b = blockIdx.x;
    int base0 = b * bcap;
    int n = min(ctr[b], bcap);

    if (tid < 64) cnt[tid] = 0;
    __syncthreads();
    for (int k = tid; k < n; k += 512) {
        int2 rec = nt_load_i2(&staging[base0 + k]);
        recs[k] = rec;
        atomicAdd(&cnt[((unsigned)rec.x) >> 18], 1);
    }
    __syncthreads();
    if (tid == 0) {
        int run = 0;
        #pragma unroll
        for (int i = 0; i < 64; ++i) { pos[i] = run; run += cnt[i]; }
    }
    __syncthreads();
    if (tid < 64) rs65[b * 65 + tid] = base0 + pos[tid];
    if (tid == 65) rs65[b * 65 + 64] = base0 + n;
    __syncthreads();
    for (int k = tid; k < n; k += 512) {
        int2 rec = recs[k];
        int rl = ((unsigned)rec.x) >> 18;
        int p = atomicAdd(&pos[rl], 1);
        staging[base0 + p] = make_int2(rec.x & 0x3FFFF, rec.y);
    }
}

// ---------- SpMM (R8 mapping): one wave per row; lane = (edge-slot q, dim t);
// 16 edges per round, 4 gathers in flight ----------

__global__ __launch_bounds__(256) void spmm_csr_kernel(
        const int* __restrict__ rs65,
        const int2* __restrict__ pairs,
        const float* __restrict__ cur,
        float* __restrict__ next) {
    int gid = blockIdx.x * blockDim.x + threadIdx.x;
    int r = gid >> 6;          // wave id = row
    if (r >= NTOT) return;
    int lane = threadIdx.x & 63;
    int q = lane >> 4;         // edge slot 0..3
    int t = lane & 15;         // dim quarter 0..15
    int b = r >> 6, i = r & 63;
    int s = rs65[b * 65 + i];
    int e = rs65[b * 65 + i + 1];
    float4 acc = make_float4(0.f, 0.f, 0.f, 0.f);
    for (int base = s; base < e; base += 16) {
        int   c[4];
        float v[4];
        #pragma unroll
        for (int k = 0; k < 4; ++k) {
            int idx = base + q + 4 * k;
            bool ok = idx < e;
            int2 cv = nt_load_i2(&pairs[ok ? idx : s]);
            c[k] = cv.x;
            v[k] = ok ? __int_as_float(cv.y) : 0.f;
        }
        #pragma unroll
        for (int k = 0; k < 4; ++k) {
            float4 g = *(const float4*)&cur[(size_t)c[k] * EMB + t * 4];
            acc.x += v[k] * g.x; acc.y += v[k] * g.y;
            acc.z += v[k] * g.z; acc.w += v[k] * g.w;
        }
    }
    #pragma unroll
    for (int o = 16; o < 64; o <<= 1) {
        acc.x += __shfl_xor(acc.x, o);
        acc.y += __shfl_xor(acc.y, o);
        acc.z += __shfl_xor(acc.z, o);
        acc.w += __shfl_xor(acc.w, o);
    }
    if (q == 0) ((float4*)&next[(size_t)r * EMB])[t] = acc;
}

// spill edges (normally zero): atomic add on top of spmm output
__global__ void spill_apply_kernel(const int4* __restrict__ spill,
                                   const int* __restrict__ spillcnt,
                                   const float* __restrict__ cur,
                                   float* __restrict__ next) {
    int n = min(*spillcnt, SPILLCAP);
    for (int idx = blockIdx.x * blockDim.x + threadIdx.x;
         idx < n * EMB; idx += gridDim.x * blockDim.x) {
        int e = idx >> 6, d = idx & 63;
        int4 rec = spill[e];
        atomicAdd(&next[(size_t)rec.x * EMB + d],
                  __int_as_float(rec.z) * cur[(size_t)rec.y * EMB + d]);
    }
}

// ---------- fallback atomic SpMM (ws too small) ----------

__global__ void spmm_atomic_kernel(const int* __restrict__ row,
                                   const int* __restrict__ col,
                                   const float* __restrict__ val,
                                   const float* __restrict__ cur,
                                   float* __restrict__ next) {
    long long idx = (long long)blockIdx.x * blockDim.x + threadIdx.x;
    if (idx >= (long long)NNZ * EMB) return;
    int e = (int)(idx >> 6);
    int d = (int)(idx & 63);
    atomicAdd(&next[row[e] * EMB + d], val[e] * cur[col[e] * EMB + d]);
}

extern "C" void kernel_launch(void* const* d_in, const int* in_sizes, int n_in,
                              void* d_out, int out_size, void* d_ws, size_t ws_size,
                              hipStream_t stream) {
    const int*   row   = (const int*)d_in[0];
    const int*   col   = (const int*)d_in[1];
    const float* val   = (const float*)d_in[2];
    const float* eu    = (const float*)d_in[3];
    const float* ei    = (const float*)d_in[4];
    const int*   users = (const int*)d_in[5];
    const int*   items = (const int*)d_in[6];
    float*       out   = (float*)d_out;

    // fixed part of workspace
    float* bufA = (float*)d_ws;                          // NTOT*EMB
    float* bufB = bufA + (size_t)NTOT * EMB;             // NTOT*EMB
    float* uacc = bufB + (size_t)NTOT * EMB;             // NQ*EMB
    float* iacc = uacc + (size_t)NQ * EMB;               // NQ*EMB
    int*   ctr  = (int*)(iacc + (size_t)NQ * EMB);       // NBKT
    int*   rs65 = ctr + NBKT;                            // NBKT*65
    int*   spillcnt = rs65 + NBKT * 65;                  // 1 (+pad to 4)
    int4*  spill = (int4*)(spillcnt + 4);                // SPILLCAP
    int2*  staging = (int2*)(spill + SPILLCAP);          // NBKT*bcap

    size_t fixed_bytes = (size_t)((char*)staging - (char*)d_ws);
    size_t need1216 = fixed_bytes + (size_t)NBKT * 1216 * sizeof(int2);
    size_t need1024 = fixed_bytes + (size_t)NBKT * 1024 * sizeof(int2);
    int bcap = (ws_size >= need1216) ? 1216 : ((ws_size >= need1024) ? 1024 : 0);

    init_cur_kernel<<<(NTOT * EMB / 4 + 255) / 256, 256, 0, stream>>>(eu, ei, bufA);
    gather_acc_kernel<true><<<(NQ * 16 + 255) / 256, 256, 0, stream>>>(users, items, bufA, uacc, iacc);

    float* cur = bufA;
    float* nxt = bufB;

    if (bcap > 0) {
        (void)hipMemsetAsync(ctr, 0, NBKT * sizeof(int), stream);
        (void)hipMemsetAsync(spillcnt, 0, 4 * sizeof(int), stream);
        append_agg_kernel<<<NAB, 1024, 0, stream>>>(row, col, val, ctr, staging,
                                                    spill, spillcnt, bcap);
        csr_fixed_kernel<<<NBKT, 512, 0, stream>>>(ctr, staging, rs65, bcap);

        for (int l = 0; l < 3; ++l) {
            spmm_csr_kernel<<<(NTOT * 64 + 255) / 256, 256, 0, stream>>>(rs65, staging, cur, nxt);
            spill_apply_kernel<<<64, 256, 0, stream>>>(spill, spillcnt, cur, nxt);
            gather_acc_kernel<false><<<(NQ * 16 + 255) / 256, 256, 0, stream>>>(users, items, nxt, uacc, iacc);
            float* t = cur; cur = nxt; nxt = t;
        }
    } else {
        // fallback: atomic SpMM
        const long long spmm_threads = (long long)NNZ * EMB;
        for (int l = 0; l < 3; ++l) {
            (void)hipMemsetAsync(nxt, 0, (size_t)NTOT * EMB * sizeof(float), stream);
            spmm_atomic_kernel<<<(int)((spmm_threads + 255) / 256), 256, 0, stream>>>(row, col, val, cur, nxt);
            gather_acc_kernel<false><<<(NQ * 16 + 255) / 256, 256, 0, stream>>>(users, items, nxt, uacc, iacc);
            float* t = cur; cur = nxt; nxt = t;
        }
    }

    dot_kernel<<<(NQ * EMB + 255) / 256, 256, 0, stream>>>(uacc, iacc, out);
}